// Round 1
// baseline (288.636 us; speedup 1.0000x reference)
//
#include <hip/hip_runtime.h>
#include <math.h>

#define N_NODES 50000
#define N_FEAT  128
#define N_EDGES 600000
#define N_POWERS 3

// 16 lanes per edge; each lane covers 8 features (2 x float4 per gathered row).
// Wave = 4 edges. Block 256 = 16 edges. grid = (37500, 3).
__global__ __launch_bounds__(256) void adj_kernel(
    const float* __restrict__ x,
    const int*   __restrict__ edge_index,   // (P, 2, E) int32
    const float* __restrict__ Wa,           // (P, 128, 3)
    const float* __restrict__ ba,           // (P, 3)
    const float* __restrict__ Wb,           // (P, 3, 1)
    const float* __restrict__ bb,           // (P, 1)
    float* __restrict__ out)                // (P, E)
{
    const int p    = blockIdx.y;
    const int tid  = threadIdx.x;
    const int lane = tid & 63;
    const int wave = tid >> 6;
    const int sub  = lane & 15;   // lane within edge group
    const int grp  = lane >> 4;   // edge group within wave

    const int f0 = sub * 8;       // this lane's feature slice [f0, f0+8)

    // Per-thread Wa fragment: fixed for the whole thread (f0 is lane-determined).
    const float* Wap = Wa + (size_t)p * N_FEAT * 3;
    float wa0[8], wa1[8], wa2[8];
    #pragma unroll
    for (int k = 0; k < 8; ++k) {
        wa0[k] = Wap[(f0 + k) * 3 + 0];
        wa1[k] = Wap[(f0 + k) * 3 + 1];
        wa2[k] = Wap[(f0 + k) * 3 + 2];
    }

    // Wave-uniform (p = blockIdx.y) -> scalar loads.
    const float ba0 = ba[p * 3 + 0], ba1 = ba[p * 3 + 1], ba2 = ba[p * 3 + 2];
    const float wb0 = Wb[p * 3 + 0], wb1 = Wb[p * 3 + 1], wb2 = Wb[p * 3 + 2];
    const float bbp = bb[p];

    const int e = blockIdx.x * 16 + wave * 4 + grp;
    if (e >= N_EDGES) return;   // exact grid: 37500*16 == 600000, kept for safety

    const int* ej = edge_index + (size_t)p * 2 * N_EDGES;  // sources  (edge_index[p][0])
    const int* ei = ej + N_EDGES;                          // targets  (edge_index[p][1])
    const int j = ej[e];
    const int i = ei[e];

    const float4* xj = (const float4*)(x + (size_t)j * N_FEAT + f0);
    const float4* xi = (const float4*)(x + (size_t)i * N_FEAT + f0);
    float4 a0 = xj[0], a1 = xj[1];
    float4 b0 = xi[0], b1 = xi[1];

    float d[8];
    d[0] = fabsf(a0.x - b0.x); d[1] = fabsf(a0.y - b0.y);
    d[2] = fabsf(a0.z - b0.z); d[3] = fabsf(a0.w - b0.w);
    d[4] = fabsf(a1.x - b1.x); d[5] = fabsf(a1.y - b1.y);
    d[6] = fabsf(a1.z - b1.z); d[7] = fabsf(a1.w - b1.w);

    float h0 = 0.f, h1 = 0.f, h2 = 0.f;
    #pragma unroll
    for (int k = 0; k < 8; ++k) {
        h0 = fmaf(d[k], wa0[k], h0);
        h1 = fmaf(d[k], wa1[k], h1);
        h2 = fmaf(d[k], wa2[k], h2);
    }

    // Butterfly reduce across the 16-lane group (masks < 16 stay in-group).
    #pragma unroll
    for (int m = 1; m < 16; m <<= 1) {
        h0 += __shfl_xor(h0, m, 64);
        h1 += __shfl_xor(h1, m, 64);
        h2 += __shfl_xor(h2, m, 64);
    }

    if (sub == 0) {
        float r0 = fmaxf(h0 + ba0, 0.f);
        float r1 = fmaxf(h1 + ba1, 0.f);
        float r2 = fmaxf(h2 + ba2, 0.f);
        float s  = fmaf(r0, wb0, fmaf(r1, wb1, fmaf(r2, wb2, bbp)));
        float w  = 1.f / (1.f + expf(-s));
        out[(size_t)p * N_EDGES + e] = w;
    }
}

extern "C" void kernel_launch(void* const* d_in, const int* in_sizes, int n_in,
                              void* d_out, int out_size, void* d_ws, size_t ws_size,
                              hipStream_t stream) {
    const float* x          = (const float*)d_in[0];
    const int*   edge_index = (const int*)d_in[1];
    const float* Wa         = (const float*)d_in[2];
    const float* ba         = (const float*)d_in[3];
    const float* Wb         = (const float*)d_in[4];
    const float* bb         = (const float*)d_in[5];
    float* out = (float*)d_out;

    dim3 grid((N_EDGES + 15) / 16, N_POWERS);
    dim3 block(256);
    adj_kernel<<<grid, block, 0, stream>>>(x, edge_index, Wa, ba, Wb, bb, out);
}

// Round 2
// 224.557 us; speedup vs baseline: 1.2854x; 1.2854x over previous
//
#include <hip/hip_runtime.h>
#include <math.h>

#define N_NODES 50000
#define N_FEAT  128
#define N_EDGES 600000
#define N_POWERS 3

__device__ __forceinline__ float bflo(unsigned u) {
    union { unsigned u; float f; } c; c.u = u << 16; return c.f;
}
__device__ __forceinline__ float bfhi(unsigned u) {
    union { unsigned u; float f; } c; c.u = u & 0xffff0000u; return c.f;
}
// round-to-nearest-even bf16 pack of (lo, hi)
__device__ __forceinline__ unsigned bfpack(float lo, float hi) {
    union { float f; unsigned u; } a, b; a.f = lo; b.f = hi;
    unsigned ua = a.u + 0x7fffu + ((a.u >> 16) & 1u);
    unsigned ub = b.u + 0x7fffu + ((b.u >> 16) & 1u);
    return (ua >> 16) | (ub & 0xffff0000u);
}

// x (50000,128) fp32 -> packed bf16 rows (64 uints/row). 8 floats/thread.
__global__ __launch_bounds__(256) void conv_kernel(const float* __restrict__ x,
                                                   unsigned* __restrict__ xb) {
    const int t = blockIdx.x * 256 + threadIdx.x;        // 800000 threads exactly
    const float4* x4 = (const float4*)x;
    float4 a = x4[(size_t)t * 2];
    float4 b = x4[(size_t)t * 2 + 1];
    uint4 o;
    o.x = bfpack(a.x, a.y);
    o.y = bfpack(a.z, a.w);
    o.z = bfpack(b.x, b.y);
    o.w = bfpack(b.z, b.w);
    ((uint4*)xb)[t] = o;
}

// 16 lanes/edge, 8 features/lane, one uint4 (8 bf16) per gathered row per lane.
__global__ __launch_bounds__(256) void adj_kernel_bf16(
    const unsigned* __restrict__ xb,        // (50000, 64) packed bf16
    const int*   __restrict__ edge_index,   // (P, 2, E) int32
    const float* __restrict__ Wa,           // (P, 128, 3)
    const float* __restrict__ ba,           // (P, 3)
    const float* __restrict__ Wb,           // (P, 3, 1)
    const float* __restrict__ bb,           // (P, 1)
    float* __restrict__ out)                // (P, E)
{
    const int p    = blockIdx.y;
    const int tid  = threadIdx.x;
    const int lane = tid & 63;
    const int wave = tid >> 6;
    const int sub  = lane & 15;
    const int grp  = lane >> 4;

    const int f0 = sub * 8;

    const float* Wap = Wa + (size_t)p * N_FEAT * 3;
    float wa0[8], wa1[8], wa2[8];
    #pragma unroll
    for (int k = 0; k < 8; ++k) {
        wa0[k] = Wap[(f0 + k) * 3 + 0];
        wa1[k] = Wap[(f0 + k) * 3 + 1];
        wa2[k] = Wap[(f0 + k) * 3 + 2];
    }

    const float ba0 = ba[p * 3 + 0], ba1 = ba[p * 3 + 1], ba2 = ba[p * 3 + 2];
    const float wb0 = Wb[p * 3 + 0], wb1 = Wb[p * 3 + 1], wb2 = Wb[p * 3 + 2];
    const float bbp = bb[p];

    const int e = blockIdx.x * 16 + wave * 4 + grp;

    const int* ej = edge_index + (size_t)p * 2 * N_EDGES;
    const int* ei = ej + N_EDGES;
    const int j = ej[e];
    const int i = ei[e];

    // row = 64 uints (256 B); lane slice = 4 uints (16 B)
    uint4 qa = *(const uint4*)(xb + (size_t)j * 64 + sub * 4);
    uint4 qb = *(const uint4*)(xb + (size_t)i * 64 + sub * 4);

    float d[8];
    d[0] = fabsf(bflo(qa.x) - bflo(qb.x));
    d[1] = fabsf(bfhi(qa.x) - bfhi(qb.x));
    d[2] = fabsf(bflo(qa.y) - bflo(qb.y));
    d[3] = fabsf(bfhi(qa.y) - bfhi(qb.y));
    d[4] = fabsf(bflo(qa.z) - bflo(qb.z));
    d[5] = fabsf(bfhi(qa.z) - bfhi(qb.z));
    d[6] = fabsf(bflo(qa.w) - bflo(qb.w));
    d[7] = fabsf(bfhi(qa.w) - bfhi(qb.w));

    float h0 = 0.f, h1 = 0.f, h2 = 0.f;
    #pragma unroll
    for (int k = 0; k < 8; ++k) {
        h0 = fmaf(d[k], wa0[k], h0);
        h1 = fmaf(d[k], wa1[k], h1);
        h2 = fmaf(d[k], wa2[k], h2);
    }

    #pragma unroll
    for (int m = 1; m < 16; m <<= 1) {
        h0 += __shfl_xor(h0, m, 64);
        h1 += __shfl_xor(h1, m, 64);
        h2 += __shfl_xor(h2, m, 64);
    }

    if (sub == 0) {
        float r0 = fmaxf(h0 + ba0, 0.f);
        float r1 = fmaxf(h1 + ba1, 0.f);
        float r2 = fmaxf(h2 + ba2, 0.f);
        float s  = fmaf(r0, wb0, fmaf(r1, wb1, fmaf(r2, wb2, bbp)));
        float w  = 1.f / (1.f + expf(-s));
        out[(size_t)p * N_EDGES + e] = w;
    }
}

// fp32 fallback (round-1 kernel) in case ws_size < 12.8 MB
__global__ __launch_bounds__(256) void adj_kernel_f32(
    const float* __restrict__ x,
    const int*   __restrict__ edge_index,
    const float* __restrict__ Wa,
    const float* __restrict__ ba,
    const float* __restrict__ Wb,
    const float* __restrict__ bb,
    float* __restrict__ out)
{
    const int p    = blockIdx.y;
    const int tid  = threadIdx.x;
    const int lane = tid & 63;
    const int wave = tid >> 6;
    const int sub  = lane & 15;
    const int grp  = lane >> 4;
    const int f0 = sub * 8;

    const float* Wap = Wa + (size_t)p * N_FEAT * 3;
    float wa0[8], wa1[8], wa2[8];
    #pragma unroll
    for (int k = 0; k < 8; ++k) {
        wa0[k] = Wap[(f0 + k) * 3 + 0];
        wa1[k] = Wap[(f0 + k) * 3 + 1];
        wa2[k] = Wap[(f0 + k) * 3 + 2];
    }
    const float ba0 = ba[p * 3 + 0], ba1 = ba[p * 3 + 1], ba2 = ba[p * 3 + 2];
    const float wb0 = Wb[p * 3 + 0], wb1 = Wb[p * 3 + 1], wb2 = Wb[p * 3 + 2];
    const float bbp = bb[p];

    const int e = blockIdx.x * 16 + wave * 4 + grp;
    const int* ej = edge_index + (size_t)p * 2 * N_EDGES;
    const int* ei = ej + N_EDGES;
    const int j = ej[e];
    const int i = ei[e];

    const float4* xj = (const float4*)(x + (size_t)j * N_FEAT + f0);
    const float4* xi = (const float4*)(x + (size_t)i * N_FEAT + f0);
    float4 a0 = xj[0], a1 = xj[1];
    float4 b0 = xi[0], b1 = xi[1];

    float d[8];
    d[0] = fabsf(a0.x - b0.x); d[1] = fabsf(a0.y - b0.y);
    d[2] = fabsf(a0.z - b0.z); d[3] = fabsf(a0.w - b0.w);
    d[4] = fabsf(a1.x - b1.x); d[5] = fabsf(a1.y - b1.y);
    d[6] = fabsf(a1.z - b1.z); d[7] = fabsf(a1.w - b1.w);

    float h0 = 0.f, h1 = 0.f, h2 = 0.f;
    #pragma unroll
    for (int k = 0; k < 8; ++k) {
        h0 = fmaf(d[k], wa0[k], h0);
        h1 = fmaf(d[k], wa1[k], h1);
        h2 = fmaf(d[k], wa2[k], h2);
    }
    #pragma unroll
    for (int m = 1; m < 16; m <<= 1) {
        h0 += __shfl_xor(h0, m, 64);
        h1 += __shfl_xor(h1, m, 64);
        h2 += __shfl_xor(h2, m, 64);
    }
    if (sub == 0) {
        float r0 = fmaxf(h0 + ba0, 0.f);
        float r1 = fmaxf(h1 + ba1, 0.f);
        float r2 = fmaxf(h2 + ba2, 0.f);
        float s  = fmaf(r0, wb0, fmaf(r1, wb1, fmaf(r2, wb2, bbp)));
        float w  = 1.f / (1.f + expf(-s));
        out[(size_t)p * N_EDGES + e] = w;
    }
}

extern "C" void kernel_launch(void* const* d_in, const int* in_sizes, int n_in,
                              void* d_out, int out_size, void* d_ws, size_t ws_size,
                              hipStream_t stream) {
    const float* x          = (const float*)d_in[0];
    const int*   edge_index = (const int*)d_in[1];
    const float* Wa         = (const float*)d_in[2];
    const float* ba         = (const float*)d_in[3];
    const float* Wb         = (const float*)d_in[4];
    const float* bb         = (const float*)d_in[5];
    float* out = (float*)d_out;

    const size_t need = (size_t)N_NODES * N_FEAT * 2;   // 12.8 MB packed bf16
    dim3 grid((N_EDGES + 15) / 16, N_POWERS);
    dim3 block(256);

    if (ws_size >= need) {
        unsigned* xb = (unsigned*)d_ws;
        conv_kernel<<<(N_NODES * N_FEAT / 8 + 255) / 256, 256, 0, stream>>>(x, xb);
        adj_kernel_bf16<<<grid, block, 0, stream>>>(xb, edge_index, Wa, ba, Wb, bb, out);
    } else {
        adj_kernel_f32<<<grid, block, 0, stream>>>(x, edge_index, Wa, ba, Wb, bb, out);
    }
}

// Round 3
// 185.753 us; speedup vs baseline: 1.5539x; 1.2089x over previous
//
#include <hip/hip_runtime.h>
#include <math.h>

#define N_NODES 50000
#define N_FEAT  128
#define N_EDGES 600000
#define N_POWERS 3

#define ITERS 25
#define EDGES_PER_BLK (32 * ITERS)   // 800; grid.x = 750

typedef _Float16 half2v __attribute__((ext_vector_type(2)));
union HU { unsigned u; half2v h; };

// ---- conversion: x fp32 -> packed f16 rows (64 uints / row) ----
__global__ __launch_bounds__(256) void conv_x(const float* __restrict__ x,
                                              unsigned* __restrict__ xh) {
    const int t = blockIdx.x * 256 + threadIdx.x;   // 800000 threads exactly
    const float4* x4 = (const float4*)x;
    float4 a = x4[(size_t)t * 2];
    float4 b = x4[(size_t)t * 2 + 1];
    HU p0, p1, p2, p3;
    p0.h = half2v{(_Float16)a.x, (_Float16)a.y};
    p1.h = half2v{(_Float16)a.z, (_Float16)a.w};
    p2.h = half2v{(_Float16)b.x, (_Float16)b.y};
    p3.h = half2v{(_Float16)b.z, (_Float16)b.w};
    ((uint4*)xh)[t] = uint4{p0.u, p1.u, p2.u, p3.u};
}

// ---- conversion: Wa fp32 (P,128,3) -> packed f16 pairs (P,64,3) uints ----
__global__ __launch_bounds__(192) void conv_wa(const float* __restrict__ Wa,
                                               unsigned* __restrict__ wah) {
    const int t = blockIdx.x * 192 + threadIdx.x;   // 576 threads
    const int c  = t % 3;
    const int pk = t / 3;
    const int k  = pk % 64;
    const int p  = pk / 64;
    float w0 = Wa[p * 384 + (2 * k) * 3 + c];
    float w1 = Wa[p * 384 + (2 * k + 1) * 3 + c];
    HU u; u.h = half2v{(_Float16)w0, (_Float16)w1};
    wah[t] = u.u;
}

template<int PAT>
__device__ __forceinline__ float swz(float v) {
    return __int_as_float(__builtin_amdgcn_ds_swizzle(__float_as_int(v), PAT));
}

// 8 lanes/edge, 16 features/lane, f16 dot2 accumulate. Persistent loop over 25 tiles.
__global__ __launch_bounds__(256) void adj_kernel_f16(
    const unsigned* __restrict__ xh,        // (50000, 64) packed f16
    const unsigned* __restrict__ wah,       // (P, 64, 3) packed f16 pairs
    const int*   __restrict__ edge_index,   // (P, 2, E) int32
    const float* __restrict__ ba,
    const float* __restrict__ Wb,
    const float* __restrict__ bb,
    float* __restrict__ out)                // (P, E)
{
    const int p    = blockIdx.y;
    const int tid  = threadIdx.x;
    const int lane = tid & 63;
    const int wave = tid >> 6;
    const int sub  = lane & 7;     // lane within edge group (8 lanes/edge)
    const int grp  = lane >> 3;    // 8 edge groups per wave

    // This thread's Wa fragment: 8 feature-pairs x 3 cols, packed f16 pairs.
    HU wa[8][3];
    {
        const unsigned* wp = wah + ((size_t)p * 64 + sub * 8) * 3;
        #pragma unroll
        for (int k = 0; k < 8; ++k) {
            wa[k][0].u = wp[k * 3 + 0];
            wa[k][1].u = wp[k * 3 + 1];
            wa[k][2].u = wp[k * 3 + 2];
        }
    }

    const float ba0 = ba[p * 3 + 0], ba1 = ba[p * 3 + 1], ba2 = ba[p * 3 + 2];
    const float wb0 = Wb[p * 3 + 0], wb1 = Wb[p * 3 + 1], wb2 = Wb[p * 3 + 2];
    const float bbp = bb[p];

    const int* ej = edge_index + (size_t)p * 2 * N_EDGES;
    const int* ei = ej + N_EDGES;
    float* outp = out + (size_t)p * N_EDGES;

    const int e_blk = blockIdx.x * EDGES_PER_BLK;
    const int eoff  = wave * 8 + grp;
    const int roff  = sub * 8;   // uint offset of this lane's 32B slice in a row

    for (int it = 0; it < ITERS; ++it) {
        const int e = e_blk + it * 32 + eoff;
        const int j = ej[e];
        const int i = ei[e];

        const unsigned* rj = xh + (size_t)j * 64 + roff;
        const unsigned* ri = xh + (size_t)i * 64 + roff;
        uint4 qa0 = *(const uint4*)(rj);
        uint4 qa1 = *(const uint4*)(rj + 4);
        uint4 qb0 = *(const uint4*)(ri);
        uint4 qb1 = *(const uint4*)(ri + 4);

        unsigned ua[8] = {qa0.x, qa0.y, qa0.z, qa0.w, qa1.x, qa1.y, qa1.z, qa1.w};
        unsigned ub[8] = {qb0.x, qb0.y, qb0.z, qb0.w, qb1.x, qb1.y, qb1.z, qb1.w};

        float h0 = 0.f, h1 = 0.f, h2 = 0.f;
        #pragma unroll
        for (int k = 0; k < 8; ++k) {
            HU a, b, d;
            a.u = ua[k]; b.u = ub[k];
            d.h = a.h - b.h;
            d.u &= 0x7fff7fffu;               // packed abs
            h0 = __builtin_amdgcn_fdot2(d.h, wa[k][0].h, h0, false);
            h1 = __builtin_amdgcn_fdot2(d.h, wa[k][1].h, h1, false);
            h2 = __builtin_amdgcn_fdot2(d.h, wa[k][2].h, h2, false);
        }

        // reduce across the 8-lane group (xor 1,2,4 stay in-group)
        h0 += swz<0x041F>(h0); h1 += swz<0x041F>(h1); h2 += swz<0x041F>(h2);
        h0 += swz<0x081F>(h0); h1 += swz<0x081F>(h1); h2 += swz<0x081F>(h2);
        h0 += swz<0x101F>(h0); h1 += swz<0x101F>(h1); h2 += swz<0x101F>(h2);

        if (sub == 0) {
            float r0 = fmaxf(h0 + ba0, 0.f);
            float r1 = fmaxf(h1 + ba1, 0.f);
            float r2 = fmaxf(h2 + ba2, 0.f);
            float s  = fmaf(r0, wb0, fmaf(r1, wb1, fmaf(r2, wb2, bbp)));
            outp[e] = 1.f / (1.f + expf(-s));
        }
    }
}

// ---- fp32 fallback (no workspace) ----
__global__ __launch_bounds__(256) void adj_kernel_f32(
    const float* __restrict__ x,
    const int*   __restrict__ edge_index,
    const float* __restrict__ Wa,
    const float* __restrict__ ba,
    const float* __restrict__ Wb,
    const float* __restrict__ bb,
    float* __restrict__ out)
{
    const int p    = blockIdx.y;
    const int tid  = threadIdx.x;
    const int lane = tid & 63;
    const int wave = tid >> 6;
    const int sub  = lane & 15;
    const int grp  = lane >> 4;
    const int f0 = sub * 8;

    const float* Wap = Wa + (size_t)p * N_FEAT * 3;
    float wa0[8], wa1[8], wa2[8];
    #pragma unroll
    for (int k = 0; k < 8; ++k) {
        wa0[k] = Wap[(f0 + k) * 3 + 0];
        wa1[k] = Wap[(f0 + k) * 3 + 1];
        wa2[k] = Wap[(f0 + k) * 3 + 2];
    }
    const float ba0 = ba[p * 3 + 0], ba1 = ba[p * 3 + 1], ba2 = ba[p * 3 + 2];
    const float wb0 = Wb[p * 3 + 0], wb1 = Wb[p * 3 + 1], wb2 = Wb[p * 3 + 2];
    const float bbp = bb[p];

    const int e = blockIdx.x * 16 + wave * 4 + grp;
    const int* ej = edge_index + (size_t)p * 2 * N_EDGES;
    const int* ei = ej + N_EDGES;
    const int j = ej[e];
    const int i = ei[e];

    const float4* xj = (const float4*)(x + (size_t)j * N_FEAT + f0);
    const float4* xi = (const float4*)(x + (size_t)i * N_FEAT + f0);
    float4 a0 = xj[0], a1 = xj[1];
    float4 b0 = xi[0], b1 = xi[1];

    float d[8];
    d[0] = fabsf(a0.x - b0.x); d[1] = fabsf(a0.y - b0.y);
    d[2] = fabsf(a0.z - b0.z); d[3] = fabsf(a0.w - b0.w);
    d[4] = fabsf(a1.x - b1.x); d[5] = fabsf(a1.y - b1.y);
    d[6] = fabsf(a1.z - b1.z); d[7] = fabsf(a1.w - b1.w);

    float h0 = 0.f, h1 = 0.f, h2 = 0.f;
    #pragma unroll
    for (int k = 0; k < 8; ++k) {
        h0 = fmaf(d[k], wa0[k], h0);
        h1 = fmaf(d[k], wa1[k], h1);
        h2 = fmaf(d[k], wa2[k], h2);
    }
    #pragma unroll
    for (int m = 1; m < 16; m <<= 1) {
        h0 += __shfl_xor(h0, m, 64);
        h1 += __shfl_xor(h1, m, 64);
        h2 += __shfl_xor(h2, m, 64);
    }
    if (sub == 0) {
        float r0 = fmaxf(h0 + ba0, 0.f);
        float r1 = fmaxf(h1 + ba1, 0.f);
        float r2 = fmaxf(h2 + ba2, 0.f);
        float s  = fmaf(r0, wb0, fmaf(r1, wb1, fmaf(r2, wb2, bbp)));
        float w  = 1.f / (1.f + expf(-s));
        out[(size_t)p * N_EDGES + e] = w;
    }
}

extern "C" void kernel_launch(void* const* d_in, const int* in_sizes, int n_in,
                              void* d_out, int out_size, void* d_ws, size_t ws_size,
                              hipStream_t stream) {
    const float* x          = (const float*)d_in[0];
    const int*   edge_index = (const int*)d_in[1];
    const float* Wa         = (const float*)d_in[2];
    const float* ba         = (const float*)d_in[3];
    const float* Wb         = (const float*)d_in[4];
    const float* bb         = (const float*)d_in[5];
    float* out = (float*)d_out;

    const size_t x_bytes  = (size_t)N_NODES * N_FEAT * 2;          // 12.8 MB
    const size_t wa_bytes = (size_t)N_POWERS * 64 * 3 * 4;         // 2304 B
    if (ws_size >= x_bytes + wa_bytes) {
        unsigned* xh  = (unsigned*)d_ws;
        unsigned* wah = (unsigned*)((char*)d_ws + x_bytes);
        conv_x<<<(N_NODES * N_FEAT / 8 + 255) / 256, 256, 0, stream>>>(x, xh);
        conv_wa<<<3, 192, 0, stream>>>(Wa, wah);
        dim3 grid(N_EDGES / EDGES_PER_BLK, N_POWERS);   // (750, 3)
        adj_kernel_f16<<<grid, 256, 0, stream>>>(xh, wah, edge_index, ba, Wb, bb, out);
    } else {
        dim3 grid((N_EDGES + 15) / 16, N_POWERS);
        adj_kernel_f32<<<grid, 256, 0, stream>>>(x, edge_index, Wa, ba, Wb, bb, out);
    }
}

// Round 4
// 180.379 us; speedup vs baseline: 1.6002x; 1.0298x over previous
//
#include <hip/hip_runtime.h>
#include <math.h>

#define N_NODES 50000
#define N_FEAT  128
#define N_EDGES 600000
#define N_POWERS 3

#define PAIRS 5
#define EDGES_PER_BLK (64 * PAIRS)   // 320; grid.x = 1875

typedef _Float16 half2v __attribute__((ext_vector_type(2)));
union HU { unsigned u; half2v h; };

// ---- conversion: x fp32 -> packed f16 rows (64 uints / row) ----
__global__ __launch_bounds__(256) void conv_x(const float* __restrict__ x,
                                              unsigned* __restrict__ xh) {
    const int t = blockIdx.x * 256 + threadIdx.x;   // 800000 threads exactly
    const float4* x4 = (const float4*)x;
    float4 a = x4[(size_t)t * 2];
    float4 b = x4[(size_t)t * 2 + 1];
    HU p0, p1, p2, p3;
    p0.h = half2v{(_Float16)a.x, (_Float16)a.y};
    p1.h = half2v{(_Float16)a.z, (_Float16)a.w};
    p2.h = half2v{(_Float16)b.x, (_Float16)b.y};
    p3.h = half2v{(_Float16)b.z, (_Float16)b.w};
    ((uint4*)xh)[t] = uint4{p0.u, p1.u, p2.u, p3.u};
}

// ---- conversion: Wa fp32 (P,128,3) -> packed f16 pairs (P,64,3) uints ----
__global__ __launch_bounds__(192) void conv_wa(const float* __restrict__ Wa,
                                               unsigned* __restrict__ wah) {
    const int t = blockIdx.x * 192 + threadIdx.x;   // 576 threads
    const int c  = t % 3;
    const int pk = t / 3;
    const int k  = pk % 64;
    const int p  = pk / 64;
    float w0 = Wa[p * 384 + (2 * k) * 3 + c];
    float w1 = Wa[p * 384 + (2 * k + 1) * 3 + c];
    HU u; u.h = half2v{(_Float16)w0, (_Float16)w1};
    wah[t] = u.u;
}

template<int PAT>
__device__ __forceinline__ float swz(float v) {
    return __int_as_float(__builtin_amdgcn_ds_swizzle(__float_as_int(v), PAT));
}

__device__ __forceinline__ void dot3_8(const uint4& qa0, const uint4& qa1,
                                       const uint4& qb0, const uint4& qb1,
                                       const HU wa[8][3],
                                       float& h0, float& h1, float& h2) {
    unsigned ua[8] = {qa0.x, qa0.y, qa0.z, qa0.w, qa1.x, qa1.y, qa1.z, qa1.w};
    unsigned ub[8] = {qb0.x, qb0.y, qb0.z, qb0.w, qb1.x, qb1.y, qb1.z, qb1.w};
    h0 = 0.f; h1 = 0.f; h2 = 0.f;
    #pragma unroll
    for (int k = 0; k < 8; ++k) {
        HU a, b, d;
        a.u = ua[k]; b.u = ub[k];
        d.h = a.h - b.h;
        d.u &= 0x7fff7fffu;               // packed abs
        h0 = __builtin_amdgcn_fdot2(d.h, wa[k][0].h, h0, false);
        h1 = __builtin_amdgcn_fdot2(d.h, wa[k][1].h, h1, false);
        h2 = __builtin_amdgcn_fdot2(d.h, wa[k][2].h, h2, false);
    }
}

// 8 lanes/edge, 16 features/lane, 2 edges interleaved per thread per iter.
__global__ __launch_bounds__(256) void adj_kernel_f16(
    const unsigned* __restrict__ xh,        // (50000, 64) packed f16
    const unsigned* __restrict__ wah,       // (P, 64, 3) packed f16 pairs
    const int*   __restrict__ edge_index,   // (P, 2, E) int32
    const float* __restrict__ ba,
    const float* __restrict__ Wb,
    const float* __restrict__ bb,
    float* __restrict__ out)                // (P, E)
{
    const int p    = blockIdx.y;
    const int tid  = threadIdx.x;
    const int lane = tid & 63;
    const int wave = tid >> 6;
    const int sub  = lane & 7;     // lane within edge group (8 lanes/edge)
    const int grp  = lane >> 3;    // 8 edge groups per wave

    // This thread's Wa fragment: 8 feature-pairs x 3 cols, packed f16 pairs.
    // Pin into VGPRs so the compiler cannot sink the loads into the loop.
    HU wa[8][3];
    {
        const unsigned* wp = wah + ((size_t)p * 64 + sub * 8) * 3;
        #pragma unroll
        for (int k = 0; k < 8; ++k) {
            wa[k][0].u = wp[k * 3 + 0];
            wa[k][1].u = wp[k * 3 + 1];
            wa[k][2].u = wp[k * 3 + 2];
        }
        #pragma unroll
        for (int k = 0; k < 8; ++k) {
            asm volatile("" : "+v"(wa[k][0].u), "+v"(wa[k][1].u), "+v"(wa[k][2].u));
        }
    }

    const float ba0 = ba[p * 3 + 0], ba1 = ba[p * 3 + 1], ba2 = ba[p * 3 + 2];
    const float wb0 = Wb[p * 3 + 0], wb1 = Wb[p * 3 + 1], wb2 = Wb[p * 3 + 2];
    const float bbp = bb[p];

    const int* ej = edge_index + (size_t)p * 2 * N_EDGES;
    const int* ei = ej + N_EDGES;
    float* outp = out + (size_t)p * N_EDGES;

    const int e_blk = blockIdx.x * EDGES_PER_BLK;
    const int eoff  = wave * 8 + grp;
    const int roff  = sub * 8;   // uint offset of this lane's 32B slice in a row

    #pragma unroll
    for (int it = 0; it < PAIRS; ++it) {
        const int e1 = e_blk + it * 64 + eoff;
        const int e2 = e1 + 32;

        // ---- issue all index loads (streamed once -> nontemporal) ----
        const int j1 = __builtin_nontemporal_load(ej + e1);
        const int i1 = __builtin_nontemporal_load(ei + e1);
        const int j2 = __builtin_nontemporal_load(ej + e2);
        const int i2 = __builtin_nontemporal_load(ei + e2);

        // ---- issue all 8 row vector loads before any compute ----
        const uint4* rj1 = (const uint4*)(xh + ((size_t)j1 << 6) + roff);
        const uint4* ri1 = (const uint4*)(xh + ((size_t)i1 << 6) + roff);
        const uint4* rj2 = (const uint4*)(xh + ((size_t)j2 << 6) + roff);
        const uint4* ri2 = (const uint4*)(xh + ((size_t)i2 << 6) + roff);
        uint4 a0 = rj1[0], a1 = rj1[1];
        uint4 b0 = ri1[0], b1 = ri1[1];
        uint4 c0 = rj2[0], c1 = rj2[1];
        uint4 d0 = ri2[0], d1 = ri2[1];

        float h0a, h1a, h2a, h0b, h1b, h2b;
        dot3_8(a0, a1, b0, b1, wa, h0a, h1a, h2a);
        dot3_8(c0, c1, d0, d1, wa, h0b, h1b, h2b);

        // reduce across the 8-lane group (xor 1,2,4 stay in-group)
        h0a += swz<0x041F>(h0a); h1a += swz<0x041F>(h1a); h2a += swz<0x041F>(h2a);
        h0b += swz<0x041F>(h0b); h1b += swz<0x041F>(h1b); h2b += swz<0x041F>(h2b);
        h0a += swz<0x081F>(h0a); h1a += swz<0x081F>(h1a); h2a += swz<0x081F>(h2a);
        h0b += swz<0x081F>(h0b); h1b += swz<0x081F>(h1b); h2b += swz<0x081F>(h2b);
        h0a += swz<0x101F>(h0a); h1a += swz<0x101F>(h1a); h2a += swz<0x101F>(h2a);
        h0b += swz<0x101F>(h0b); h1b += swz<0x101F>(h1b); h2b += swz<0x101F>(h2b);

        if (sub == 0) {
            float r0 = fmaxf(h0a + ba0, 0.f);
            float r1 = fmaxf(h1a + ba1, 0.f);
            float r2 = fmaxf(h2a + ba2, 0.f);
            float s  = fmaf(r0, wb0, fmaf(r1, wb1, fmaf(r2, wb2, bbp)));
            __builtin_nontemporal_store(1.f / (1.f + __expf(-s)), outp + e1);

            r0 = fmaxf(h0b + ba0, 0.f);
            r1 = fmaxf(h1b + ba1, 0.f);
            r2 = fmaxf(h2b + ba2, 0.f);
            s  = fmaf(r0, wb0, fmaf(r1, wb1, fmaf(r2, wb2, bbp)));
            __builtin_nontemporal_store(1.f / (1.f + __expf(-s)), outp + e2);
        }
    }
}

// ---- fp32 fallback (no workspace) ----
__global__ __launch_bounds__(256) void adj_kernel_f32(
    const float* __restrict__ x,
    const int*   __restrict__ edge_index,
    const float* __restrict__ Wa,
    const float* __restrict__ ba,
    const float* __restrict__ Wb,
    const float* __restrict__ bb,
    float* __restrict__ out)
{
    const int p    = blockIdx.y;
    const int tid  = threadIdx.x;
    const int lane = tid & 63;
    const int wave = tid >> 6;
    const int sub  = lane & 15;
    const int grp  = lane >> 4;
    const int f0 = sub * 8;

    const float* Wap = Wa + (size_t)p * N_FEAT * 3;
    float wa0[8], wa1[8], wa2[8];
    #pragma unroll
    for (int k = 0; k < 8; ++k) {
        wa0[k] = Wap[(f0 + k) * 3 + 0];
        wa1[k] = Wap[(f0 + k) * 3 + 1];
        wa2[k] = Wap[(f0 + k) * 3 + 2];
    }
    const float ba0 = ba[p * 3 + 0], ba1 = ba[p * 3 + 1], ba2 = ba[p * 3 + 2];
    const float wb0 = Wb[p * 3 + 0], wb1 = Wb[p * 3 + 1], wb2 = Wb[p * 3 + 2];
    const float bbp = bb[p];

    const int e = blockIdx.x * 16 + wave * 4 + grp;
    const int* ej = edge_index + (size_t)p * 2 * N_EDGES;
    const int* ei = ej + N_EDGES;
    const int j = ej[e];
    const int i = ei[e];

    const float4* xj = (const float4*)(x + (size_t)j * N_FEAT + f0);
    const float4* xi = (const float4*)(x + (size_t)i * N_FEAT + f0);
    float4 a0 = xj[0], a1 = xj[1];
    float4 b0 = xi[0], b1 = xi[1];

    float d[8];
    d[0] = fabsf(a0.x - b0.x); d[1] = fabsf(a0.y - b0.y);
    d[2] = fabsf(a0.z - b0.z); d[3] = fabsf(a0.w - b0.w);
    d[4] = fabsf(a1.x - b1.x); d[5] = fabsf(a1.y - b1.y);
    d[6] = fabsf(a1.z - b1.z); d[7] = fabsf(a1.w - b1.w);

    float h0 = 0.f, h1 = 0.f, h2 = 0.f;
    #pragma unroll
    for (int k = 0; k < 8; ++k) {
        h0 = fmaf(d[k], wa0[k], h0);
        h1 = fmaf(d[k], wa1[k], h1);
        h2 = fmaf(d[k], wa2[k], h2);
    }
    #pragma unroll
    for (int m = 1; m < 16; m <<= 1) {
        h0 += __shfl_xor(h0, m, 64);
        h1 += __shfl_xor(h1, m, 64);
        h2 += __shfl_xor(h2, m, 64);
    }
    if (sub == 0) {
        float r0 = fmaxf(h0 + ba0, 0.f);
        float r1 = fmaxf(h1 + ba1, 0.f);
        float r2 = fmaxf(h2 + ba2, 0.f);
        float s  = fmaf(r0, wb0, fmaf(r1, wb1, fmaf(r2, wb2, bbp)));
        float w  = 1.f / (1.f + expf(-s));
        out[(size_t)p * N_EDGES + e] = w;
    }
}

extern "C" void kernel_launch(void* const* d_in, const int* in_sizes, int n_in,
                              void* d_out, int out_size, void* d_ws, size_t ws_size,
                              hipStream_t stream) {
    const float* x          = (const float*)d_in[0];
    const int*   edge_index = (const int*)d_in[1];
    const float* Wa         = (const float*)d_in[2];
    const float* ba         = (const float*)d_in[3];
    const float* Wb         = (const float*)d_in[4];
    const float* bb         = (const float*)d_in[5];
    float* out = (float*)d_out;

    const size_t x_bytes  = (size_t)N_NODES * N_FEAT * 2;          // 12.8 MB
    const size_t wa_bytes = (size_t)N_POWERS * 64 * 3 * 4;         // 2304 B
    if (ws_size >= x_bytes + wa_bytes) {
        unsigned* xh  = (unsigned*)d_ws;
        unsigned* wah = (unsigned*)((char*)d_ws + x_bytes);
        conv_x<<<(N_NODES * N_FEAT / 8 + 255) / 256, 256, 0, stream>>>(x, xh);
        conv_wa<<<3, 192, 0, stream>>>(Wa, wah);
        dim3 grid(N_EDGES / EDGES_PER_BLK, N_POWERS);   // (1875, 3)
        adj_kernel_f16<<<grid, 256, 0, stream>>>(xh, wah, edge_index, ba, Wb, bb, out);
    } else {
        dim3 grid((N_EDGES + 15) / 16, N_POWERS);
        adj_kernel_f32<<<grid, 256, 0, stream>>>(x, edge_index, Wa, ba, Wb, bb, out);
    }
}